// Round 2
// baseline (6222.028 us; speedup 1.0000x reference)
//
#include <hip/hip_runtime.h>
#include <hip/hip_bf16.h>
#include <cstdint>

#define NV 50257
#define LS 50304
#define HD 512
#define BS 64
#define TE 256

typedef __attribute__((ext_vector_type(8))) short short8;
typedef __attribute__((ext_vector_type(4))) float floatx4;

__device__ __forceinline__ floatx4 mm_bf16(short8 a, short8 b, floatx4 c) {
    return __builtin_amdgcn_mfma_f32_16x16x32_bf16(a, b, c, 0, 0, 0);
}

__device__ __forceinline__ short cvt_bf(float f) {
    union { float f; unsigned u; } v; v.f = f;
    unsigned r = (v.u + 0x7fffu + ((v.u >> 16) & 1u)) >> 16;
    return (short)r;
}

__device__ __forceinline__ float sigm_f(float x) {
    x = fminf(fmaxf(x, -30.f), 30.f);
    return 1.f / (1.f + __expf(-x));
}
__device__ __forceinline__ float tanh_f(float x) {
    x = fminf(fmaxf(x, -15.f), 15.f);
    float e = __expf(2.f * x);
    return (e - 1.f) / (e + 1.f);
}

__global__ void k_zero(unsigned* __restrict__ p, int n) {
    int i = blockIdx.x * 256 + threadIdx.x;
    if (i < n) p[i] = 0u;
}

// Build permuted bf16 combined weight: Wc[j'][0:512]=W_ih row, [512:1024]=W_hh row,
// where j' = 4*kcell + gate  <->  old row = gate*512 + kcell  (gate order i,f,g,o).
__global__ __launch_bounds__(256) void k_prep(
    const float* __restrict__ W_ih, const float* __restrict__ W_hh,
    short* __restrict__ Wc) {
    int jp = blockIdx.x;              // 0..2047
    int g = jp & 3, kc = jp >> 2;
    const float* si = W_ih + (long)(g * 512 + kc) * HD;
    const float* sh = W_hh + (long)(g * 512 + kc) * HD;
    short* dst = Wc + (long)jp * 1024;
    for (int k = threadIdx.x; k < 512; k += 256) {
        dst[k]       = cvt_bf(si[k]);
        dst[512 + k] = cvt_bf(sh[k]);
    }
}

// Persistent encoder+decoder. 128 blocks = 4 batch-groups(16 b) x 32 j-slices(64 j').
// Per step: gates[b, j'] = [x_t | h_{t-1}] (K=1024) @ Wc^T via 16x16x32 bf16 MFMA,
// cell update local (permuted rows => complete i,f,g,o quadruples per slice),
// h written bf16 to hs ([t][b][k]) and hsT ([t][k][b]); spin-sync per step per group.
__global__ __launch_bounds__(256) void k_enc(
    const int* __restrict__ lines, const int* __restrict__ tlines,
    const float* __restrict__ emb_in, const float* __restrict__ emb_tgt,
    const short* __restrict__ Wc,
    const float* __restrict__ b_ih, const float* __restrict__ b_hh,
    short* __restrict__ hss, short* __restrict__ hsts,
    float* __restrict__ h255, unsigned* __restrict__ cnt) {
    const int slice = blockIdx.x & 31, bg = blockIdx.x >> 5;
    const int tid = threadIdx.x, w = tid >> 6, l = tid & 63;
    const int l15 = l & 15, lq = l >> 4;
    const int bglob = bg * 16 + l15;          // batch row for both A-frags and cell
    const int jw = slice * 64 + w * 16;       // wave's j' base (global)
    __shared__ float gate_lds[4][16][17];
    __shared__ float c_lds[16][17];
    const int kcl = w * 4 + lq;               // block-local cell 0..15
    const int kcg = slice * 16 + kcl;         // global cell 0..511
    float bsum[4];
#pragma unroll
    for (int g = 0; g < 4; g++) bsum[g] = b_ih[g * 512 + kcg] + b_hh[g * 512 + kcg];

    unsigned* my_cnt = cnt + bg * 257;

    for (int t = 0; t <= 256; t++) {
        // ---- x-phase (independent of recurrence) ----
        int idx = (t < TE) ? lines[t * BS + bglob] : tlines[bglob];
        const float* xr = ((t < TE) ? emb_in : emb_tgt) + (long)idx * HD;
        floatx4 acc0 = {0.f, 0.f, 0.f, 0.f}, acc1 = {0.f, 0.f, 0.f, 0.f};
#pragma unroll 4
        for (int kt = 0; kt < 16; kt++) {
            int k = kt * 32 + lq * 8;
            float4 u0 = *(const float4*)(xr + k);
            float4 u1 = *(const float4*)(xr + k + 4);
            short8 af;
            af[0] = cvt_bf(u0.x); af[1] = cvt_bf(u0.y);
            af[2] = cvt_bf(u0.z); af[3] = cvt_bf(u0.w);
            af[4] = cvt_bf(u1.x); af[5] = cvt_bf(u1.y);
            af[6] = cvt_bf(u1.z); af[7] = cvt_bf(u1.w);
            short8 bf = *(const short8*)(Wc + (long)(jw + l15) * 1024 + k);
            if (kt & 1) acc1 = mm_bf16(af, bf, acc1);
            else        acc0 = mm_bf16(af, bf, acc0);
        }
        // ---- wait for h[t-1] from all 32 slices of this batch-group ----
        if (t > 0) {
            if (tid == 0) {
                while (__hip_atomic_load(&my_cnt[t - 1], __ATOMIC_RELAXED,
                                         __HIP_MEMORY_SCOPE_AGENT) < 32u)
                    __builtin_amdgcn_s_sleep(1);
                (void)__hip_atomic_load(&my_cnt[t - 1], __ATOMIC_ACQUIRE,
                                        __HIP_MEMORY_SCOPE_AGENT);
            }
            __syncthreads();
            const short* hrow = hss + ((long)(t - 1) * BS + bglob) * HD;
#pragma unroll 4
            for (int kt = 0; kt < 16; kt++) {
                int k = kt * 32 + lq * 8;
                short8 af = *(const short8*)(hrow + k);
                short8 bf = *(const short8*)(Wc + (long)(jw + l15) * 1024 + 512 + k);
                if (kt & 1) acc1 = mm_bf16(af, bf, acc1);
                else        acc0 = mm_bf16(af, bf, acc0);
            }
        }
        floatx4 D = acc0 + acc1;
        // D: row(b) = lq*4+r, col(j'loc) = l15 — stage to LDS (per-wave private)
#pragma unroll
        for (int r = 0; r < 4; r++) gate_lds[w][lq * 4 + r][l15] = D[r];
        // cell update: lane -> (b = l15, cell = kcl)
        float gi = gate_lds[w][l15][lq * 4 + 0] + bsum[0];
        float gf = gate_lds[w][l15][lq * 4 + 1] + bsum[1];
        float gg = gate_lds[w][l15][lq * 4 + 2] + bsum[2];
        float go = gate_lds[w][l15][lq * 4 + 3] + bsum[3];
        float iv = sigm_f(gi), fv = sigm_f(gf), gv = tanh_f(gg), ov = sigm_f(go);
        float c_old = (t > 0) ? c_lds[l15][kcl] : 0.f;
        float c_new = fv * c_old + iv * gv;
        c_lds[l15][kcl] = c_new;
        float hv = ov * tanh_f(c_new);
        short hb = cvt_bf(hv);
        hss[((long)t * BS + bglob) * HD + kcg] = hb;
        hsts[((long)t * HD + kcg) * BS + bglob] = hb;
        if (t == 255) h255[(long)bglob * HD + kcg] = hv;
        __threadfence();
        __syncthreads();
        if (tid == 0)
            __hip_atomic_fetch_add(&my_cnt[t], 1u, __ATOMIC_RELEASE,
                                   __HIP_MEMORY_SCOPE_AGENT);
    }
}

// logits[b][v] = h255[b][:] . W_out[v][:] + b_out[v].  grid 786, block 256. fp32.
__global__ __launch_bounds__(256) void k_logits(
    const float* __restrict__ hsrow, const float* __restrict__ W_out,
    const float* __restrict__ b_out, float* __restrict__ logits) {
    __shared__ float Ast[32][68];
    __shared__ float Bst[32][68];
    const int v0 = blockIdx.x * 64;
    const int tid = threadIdx.x;
    const int tx = tid & 15, ty = tid >> 4;
    const int lr = tid >> 2;
    const int lc = (tid & 3) * 8;
    int vr = v0 + lr; if (vr > NV - 1) vr = NV - 1;
    const float* arow = hsrow + (long)lr * HD + lc;
    const float* wrow = W_out + (long)vr * HD + lc;
    float acc[4][4] = {};
    for (int k0 = 0; k0 < HD; k0 += 32) {
        float4 a0 = *(const float4*)(arow + k0);
        float4 a1 = *(const float4*)(arow + k0 + 4);
        float4 b0 = *(const float4*)(wrow + k0);
        float4 b1 = *(const float4*)(wrow + k0 + 4);
        Ast[lc + 0][lr] = a0.x; Ast[lc + 1][lr] = a0.y;
        Ast[lc + 2][lr] = a0.z; Ast[lc + 3][lr] = a0.w;
        Ast[lc + 4][lr] = a1.x; Ast[lc + 5][lr] = a1.y;
        Ast[lc + 6][lr] = a1.z; Ast[lc + 7][lr] = a1.w;
        Bst[lc + 0][lr] = b0.x; Bst[lc + 1][lr] = b0.y;
        Bst[lc + 2][lr] = b0.z; Bst[lc + 3][lr] = b0.w;
        Bst[lc + 4][lr] = b1.x; Bst[lc + 5][lr] = b1.y;
        Bst[lc + 6][lr] = b1.z; Bst[lc + 7][lr] = b1.w;
        __syncthreads();
#pragma unroll
        for (int kk = 0; kk < 32; kk++) {
            float av[4], bv[4];
            *(float4*)av = *(const float4*)&Ast[kk][ty * 4];
            *(float4*)bv = *(const float4*)&Bst[kk][tx * 4];
#pragma unroll
            for (int i = 0; i < 4; i++)
#pragma unroll
                for (int j = 0; j < 4; j++)
                    acc[i][j] = fmaf(av[i], bv[j], acc[i][j]);
        }
        __syncthreads();
    }
#pragma unroll
    for (int i = 0; i < 4; i++) {
        int b = ty * 4 + i;
#pragma unroll
        for (int j = 0; j < 4; j++) {
            int v = v0 + tx * 4 + j;
            if (v < NV) logits[(long)b * LS + v] = acc[i][j] + b_out[v];
        }
    }
}

__global__ __launch_bounds__(256) void k_lse(
    const float* __restrict__ logits, float* __restrict__ lse) {
    const int b = blockIdx.x;
    const float* row = logits + (long)b * LS;
    float m = -1e30f, s = 0.f;
    for (int v = threadIdx.x; v < NV; v += 256) {
        float x = row[v];
        if (x > m) { s = s * __expf(m - x) + 1.f; m = x; }
        else s += __expf(x - m);
    }
    for (int off = 32; off; off >>= 1) {
        float m2 = __shfl_down(m, off);
        float s2 = __shfl_down(s, off);
        float M = fmaxf(m, m2);
        s = s * __expf(m - M) + s2 * __expf(m2 - M);
        m = M;
    }
    __shared__ float ms[4], ss[4];
    int wid = threadIdx.x >> 6, lane = threadIdx.x & 63;
    if (lane == 0) { ms[wid] = m; ss[wid] = s; }
    __syncthreads();
    if (threadIdx.x == 0) {
        m = ms[0]; s = ss[0];
        for (int w = 1; w < 4; w++) {
            float M = fmaxf(m, ms[w]);
            s = s * __expf(m - M) + ss[w] * __expf(ms[w] - M);
            m = M;
        }
        lse[b] = m + __logf(s);
    }
}

__global__ __launch_bounds__(64) void k_loss(
    const float* __restrict__ logits, const float* __restrict__ lse,
    const int* __restrict__ tlines, float* __restrict__ out0) {
    int b = threadIdx.x;
    float v = logits[(long)b * LS + tlines[b]] - lse[b];
    for (int off = 32; off; off >>= 1) v += __shfl_down(v, off);
    if (b == 0) out0[0] = -v * (1.f / 64.f);
}

// S[t][h][e] = sum_b ht[b][h]*hs[t][b][e] via bf16 MFMA on hsT ([t][k][b] layout):
// A[m=h][k=b] = hsT[256][h][b] (contiguous in b), B[k=b][n=e] = hsT[t][e][b].
// grid (64, 4): 8x8 tiles of 64x64 over (h,e), 4 t-chunks of 64. block 256.
__global__ __launch_bounds__(256) void k_attn(
    const short* __restrict__ hsts, float* __restrict__ eS0, float* __restrict__ part) {
    const int hti = blockIdx.x >> 3, eti = blockIdx.x & 7;
    const int tc = blockIdx.y;
    const int w = threadIdx.x >> 6, l = threadIdx.x & 63;
    const int l15 = l & 15, lq = l >> 4;
    short8 a[4][2];
#pragma unroll
    for (int mi = 0; mi < 4; mi++)
#pragma unroll
        for (int kb = 0; kb < 2; kb++) {
            int h = hti * 64 + mi * 16 + l15;
            int b = kb * 32 + lq * 8;
            a[mi][kb] = *(const short8*)(hsts + ((long)TE * HD + h) * BS + b);
        }
    const int eg = eti * 64 + w * 16 + l15;
    float ps[4][4] = {};
    for (int dt = 0; dt < 64; dt++) {
        int t = tc * 64 + dt;
        short8 bf0 = *(const short8*)(hsts + ((long)t * HD + eg) * BS + lq * 8);
        short8 bf1 = *(const short8*)(hsts + ((long)t * HD + eg) * BS + 32 + lq * 8);
#pragma unroll
        for (int mi = 0; mi < 4; mi++) {
            floatx4 acc = {0.f, 0.f, 0.f, 0.f};
            acc = mm_bf16(a[mi][0], bf0, acc);
            acc = mm_bf16(a[mi][1], bf1, acc);
#pragma unroll
            for (int r = 0; r < 4; r++) {
                float e = __expf(acc[r]);
                ps[mi][r] += e;
                if (t == 0) {
                    int hg = hti * 64 + mi * 16 + lq * 4 + r;
                    eS0[(long)hg * HD + eg] = e;
                }
            }
        }
    }
#pragma unroll
    for (int mi = 0; mi < 4; mi++)
#pragma unroll
        for (int r = 0; r < 4; r++) {
            int hg = hti * 64 + mi * 16 + lq * 4 + r;
            part[(long)tc * 262144 + (long)hg * HD + eg] = ps[mi][r];
        }
}

__global__ __launch_bounds__(256) void k_attn_fin(
    const float* __restrict__ eS0, const float* __restrict__ part,
    float* __restrict__ outat) {
    long i = (long)blockIdx.x * 256 + threadIdx.x;
    float d = part[i] + part[262144 + i] + part[2L * 262144 + i] + part[3L * 262144 + i];
    outat[i] = eS0[i] / d;
}

extern "C" void kernel_launch(void* const* d_in, const int* in_sizes, int n_in,
                              void* d_out, int out_size, void* d_ws, size_t ws_size,
                              hipStream_t stream) {
    (void)in_sizes; (void)n_in; (void)out_size; (void)ws_size;
    const int* input_lines  = (const int*)d_in[0];
    const int* target_lines = (const int*)d_in[1];
    const float* emb_in  = (const float*)d_in[2];
    const float* emb_tgt = (const float*)d_in[3];
    const float* W_ih = (const float*)d_in[4];
    const float* W_hh = (const float*)d_in[5];
    const float* b_ih = (const float*)d_in[6];
    const float* b_hh = (const float*)d_in[7];
    const float* W_out = (const float*)d_in[8];
    const float* b_out = (const float*)d_in[9];
    float* out = (float*)d_out;
    char* ws = (char*)d_ws;

    short*    Wc     = (short*)   (ws + 0);           //  4,194,304 B
    short*    hs     = (short*)   (ws + 4194304);     // 16,842,752 B
    short*    hsT    = (short*)   (ws + 21037056);    // 16,842,752 B
    float*    h255   = (float*)   (ws + 37879808);    //    131,072 B
    float*    logits = (float*)   (ws + 38010880);    // 12,877,824 B
    float*    lse    = (float*)   (ws + 50888704);    //        256 B
    float*    eS0    = (float*)   (ws + 50888960);    //  1,048,576 B
    float*    part   = (float*)   (ws + 51937536);    //  4,194,304 B
    unsigned* cnt    = (unsigned*)(ws + 56131840);    //      4,112 B

    hipLaunchKernelGGL(k_zero, dim3(5), dim3(256), 0, stream, cnt, 4 * 257);
    hipLaunchKernelGGL(k_prep, dim3(2048), dim3(256), 0, stream, W_ih, W_hh, Wc);
    hipLaunchKernelGGL(k_enc, dim3(128), dim3(256), 0, stream,
                       input_lines, target_lines, emb_in, emb_tgt, Wc,
                       b_ih, b_hh, hs, hsT, h255, cnt);
    hipLaunchKernelGGL(k_logits, dim3(786), dim3(256), 0, stream,
                       h255, W_out, b_out, logits);
    hipLaunchKernelGGL(k_lse, dim3(64), dim3(256), 0, stream, logits, lse);
    hipLaunchKernelGGL(k_loss, dim3(1), dim3(64), 0, stream,
                       logits, lse, target_lines, out);
    hipLaunchKernelGGL(k_attn, dim3(64, 4), dim3(256), 0, stream, hsT, eS0, part);
    hipLaunchKernelGGL(k_attn_fin, dim3(1024), dim3(256), 0, stream, eS0, part, out + 1);
}

// Round 3
// 4379.478 us; speedup vs baseline: 1.4207x; 1.4207x over previous
//
#include <hip/hip_runtime.h>
#include <hip/hip_bf16.h>
#include <cstdint>

#define NV 50257
#define LS 50304
#define HD 512
#define BS 64
#define TE 256
#define HSTR 520   // LDS staged-h row stride in ushorts (512 + 8 pad)

typedef __attribute__((ext_vector_type(8))) short short8;
typedef __attribute__((ext_vector_type(4))) float floatx4;

__device__ __forceinline__ floatx4 mm_bf16(short8 a, short8 b, floatx4 c) {
    return __builtin_amdgcn_mfma_f32_16x16x32_bf16(a, b, c, 0, 0, 0);
}

__device__ __forceinline__ short cvt_bf(float f) {
    union { float f; unsigned u; } v; v.f = f;
    unsigned r = (v.u + 0x7fffu + ((v.u >> 16) & 1u)) >> 16;
    return (short)r;
}

__device__ __forceinline__ float sigm_f(float x) {
    x = fminf(fmaxf(x, -30.f), 30.f);
    return 1.f / (1.f + __expf(-x));
}
__device__ __forceinline__ float tanh_f(float x) {
    x = fminf(fmaxf(x, -15.f), 15.f);
    float e = __expf(2.f * x);
    return (e - 1.f) / (e + 1.f);
}

__global__ void k_zero(unsigned* __restrict__ p, int n) {
    int i = blockIdx.x * 256 + threadIdx.x;
    if (i < n) p[i] = 0u;
}

// Permuted bf16 combined weights: Wc[j'][0:512]=W_ih row, [512:1024]=W_hh row,
// j' = 4*kcell + gate  <->  old row = gate*512 + kcell (gate order i,f,g,o).
__global__ __launch_bounds__(256) void k_prep(
    const float* __restrict__ W_ih, const float* __restrict__ W_hh,
    short* __restrict__ Wc) {
    int jp = blockIdx.x;
    int g = jp & 3, kc = jp >> 2;
    const float* si = W_ih + (long)(g * 512 + kc) * HD;
    const float* sh = W_hh + (long)(g * 512 + kc) * HD;
    short* dst = Wc + (long)jp * 1024;
    for (int k = threadIdx.x; k < 512; k += 256) {
        dst[k]       = cvt_bf(si[k]);
        dst[512 + k] = cvt_bf(sh[k]);
    }
}

// Persistent encoder+decoder. 128 blocks = 4 batch-groups(16 b) x 32 j-slices.
// h exchanged cross-block via L3: packed bf16-pair words in hsx[t][512 k][32 bpair]
// written with relaxed agent atomics (sc1, bypass L2), flags via relaxed agent
// fetch_add after s_waitcnt vmcnt(0). NO fences => no per-step L2 writeback.
// hsx doubles as the [t][k][b] bf16 tensor k_attn consumes.
__global__ __launch_bounds__(256) void k_enc(
    const int* __restrict__ lines, const int* __restrict__ tlines,
    const float* __restrict__ emb_in, const float* __restrict__ emb_tgt,
    const short* __restrict__ Wc,
    const float* __restrict__ b_ih, const float* __restrict__ b_hh,
    unsigned* __restrict__ hsx, float* __restrict__ h255,
    unsigned* __restrict__ cnt) {
    const int slice = blockIdx.x & 31, bg = blockIdx.x >> 5;
    const int tid = threadIdx.x, w = tid >> 6, l = tid & 63;
    const int l15 = l & 15, lq = l >> 4;
    const int bglob = bg * 16 + l15;
    const int jw = slice * 64 + w * 16;
    const int kcl = w * 4 + lq;
    const int kcg = slice * 16 + kcl;
    __shared__ unsigned short hA[16 * HSTR];
    __shared__ float gate_lds[4][16][17];
    __shared__ float c_lds[16][17];
    float bsum[4];
#pragma unroll
    for (int g = 0; g < 4; g++) bsum[g] = b_ih[g * 512 + kcg] + b_hh[g * 512 + kcg];
    unsigned* my_cnt = cnt + bg * 257;
    const int sm = tid & 3, sk = tid >> 2;
    const short* WcB = Wc + (long)(jw + l15) * 1024;

    floatx4 xacc0 = {0.f,0.f,0.f,0.f}, xacc1 = {0.f,0.f,0.f,0.f};
    {   // x-phase prologue for t=0
        int idx = lines[bglob];
        const float* xr = emb_in + (long)idx * HD;
#pragma unroll 4
        for (int kt = 0; kt < 16; kt++) {
            int k = kt * 32 + lq * 8;
            float4 u0 = *(const float4*)(xr + k);
            float4 u1 = *(const float4*)(xr + k + 4);
            short8 af;
            af[0]=cvt_bf(u0.x); af[1]=cvt_bf(u0.y); af[2]=cvt_bf(u0.z); af[3]=cvt_bf(u0.w);
            af[4]=cvt_bf(u1.x); af[5]=cvt_bf(u1.y); af[6]=cvt_bf(u1.z); af[7]=cvt_bf(u1.w);
            short8 bf = *(const short8*)(WcB + k);
            if (kt & 1) xacc1 = mm_bf16(af, bf, xacc1);
            else        xacc0 = mm_bf16(af, bf, xacc0);
        }
    }

    for (int t = 0; t <= 256; t++) {
        floatx4 acc0 = xacc0, acc1 = xacc1;
        if (t > 0) {
            if (tid == 0) {
                while (__hip_atomic_load(&my_cnt[t - 1], __ATOMIC_RELAXED,
                                         __HIP_MEMORY_SCOPE_AGENT) < 32u)
                    __builtin_amdgcn_s_sleep(1);
            }
            __syncthreads();
            // stage h[t-1] (group's 16 b x 512 k) from L3 into LDS, transposing
            // from [k][bpair] words to [b][k] rows for ds_read_b128 A-frags.
#pragma unroll
            for (int j = 0; j < 8; j++) {
                int k = sk + 64 * j;
                unsigned long long v = __hip_atomic_load(
                    (const unsigned long long*)(hsx + ((long)(t - 1) * 512 + k) * 32 + bg * 8 + sm * 2),
                    __ATOMIC_RELAXED, __HIP_MEMORY_SCOPE_AGENT);
                hA[(4 * sm + 0) * HSTR + k] = (unsigned short)(v);
                hA[(4 * sm + 1) * HSTR + k] = (unsigned short)(v >> 16);
                hA[(4 * sm + 2) * HSTR + k] = (unsigned short)(v >> 32);
                hA[(4 * sm + 3) * HSTR + k] = (unsigned short)(v >> 48);
            }
            __syncthreads();
#pragma unroll 4
            for (int kt = 0; kt < 16; kt++) {
                int k = kt * 32 + lq * 8;
                short8 af = *(const short8*)((const short*)&hA[l15 * HSTR + k]);
                short8 bf = *(const short8*)(WcB + 512 + k);
                if (kt & 1) acc1 = mm_bf16(af, bf, acc1);
                else        acc0 = mm_bf16(af, bf, acc0);
            }
        }
        floatx4 D = acc0 + acc1;
#pragma unroll
        for (int r = 0; r < 4; r++) gate_lds[w][lq * 4 + r][l15] = D[r];
        float gi = gate_lds[w][l15][lq * 4 + 0] + bsum[0];
        float gf = gate_lds[w][l15][lq * 4 + 1] + bsum[1];
        float gg = gate_lds[w][l15][lq * 4 + 2] + bsum[2];
        float go = gate_lds[w][l15][lq * 4 + 3] + bsum[3];
        float iv = sigm_f(gi), fv = sigm_f(gf), gv = tanh_f(gg), ov = sigm_f(go);
        float c_old = (t > 0) ? c_lds[l15][kcl] : 0.f;
        float c_new = fv * c_old + iv * gv;
        c_lds[l15][kcl] = c_new;
        float hv = ov * tanh_f(c_new);
        if (t == 255) h255[(long)bglob * HD + kcg] = hv;
        unsigned hb = (unsigned short)cvt_bf(hv);
        unsigned ot = __shfl_xor(hb, 1);
        if ((l & 1) == 0) {
            unsigned word = hb | (ot << 16);
            __hip_atomic_store(hsx + ((long)t * 512 + kcg) * 32 + bg * 8 + (l15 >> 1),
                               word, __ATOMIC_RELAXED, __HIP_MEMORY_SCOPE_AGENT);
        }
        asm volatile("s_waitcnt vmcnt(0)" ::: "memory");
        __syncthreads();
        if (tid == 0)
            __hip_atomic_fetch_add(&my_cnt[t], 1u, __ATOMIC_RELAXED,
                                   __HIP_MEMORY_SCOPE_AGENT);
        if (t < 256) {   // x-phase for t+1, hidden behind other slices' step t
            int tt = t + 1;
            int idx = (tt < TE) ? lines[tt * BS + bglob] : tlines[bglob];
            const float* xr = ((tt < TE) ? emb_in : emb_tgt) + (long)idx * HD;
            xacc0 = (floatx4){0.f,0.f,0.f,0.f}; xacc1 = (floatx4){0.f,0.f,0.f,0.f};
#pragma unroll 4
            for (int kt = 0; kt < 16; kt++) {
                int k = kt * 32 + lq * 8;
                float4 u0 = *(const float4*)(xr + k);
                float4 u1 = *(const float4*)(xr + k + 4);
                short8 af;
                af[0]=cvt_bf(u0.x); af[1]=cvt_bf(u0.y); af[2]=cvt_bf(u0.z); af[3]=cvt_bf(u0.w);
                af[4]=cvt_bf(u1.x); af[5]=cvt_bf(u1.y); af[6]=cvt_bf(u1.z); af[7]=cvt_bf(u1.w);
                short8 bf = *(const short8*)(WcB + k);
                if (kt & 1) xacc1 = mm_bf16(af, bf, xacc1);
                else        xacc0 = mm_bf16(af, bf, xacc0);
            }
        }
    }
}

// logits[b][v] = h255[b][:] . W_out[v][:] + b_out[v].  grid 786, block 256. fp32.
__global__ __launch_bounds__(256) void k_logits(
    const float* __restrict__ hsrow, const float* __restrict__ W_out,
    const float* __restrict__ b_out, float* __restrict__ logits) {
    __shared__ float Ast[32][68];
    __shared__ float Bst[32][68];
    const int v0 = blockIdx.x * 64;
    const int tid = threadIdx.x;
    const int tx = tid & 15, ty = tid >> 4;
    const int lr = tid >> 2;
    const int lc = (tid & 3) * 8;
    int vr = v0 + lr; if (vr > NV - 1) vr = NV - 1;
    const float* arow = hsrow + (long)lr * HD + lc;
    const float* wrow = W_out + (long)vr * HD + lc;
    float acc[4][4] = {};
    for (int k0 = 0; k0 < HD; k0 += 32) {
        float4 a0 = *(const float4*)(arow + k0);
        float4 a1 = *(const float4*)(arow + k0 + 4);
        float4 b0 = *(const float4*)(wrow + k0);
        float4 b1 = *(const float4*)(wrow + k0 + 4);
        Ast[lc + 0][lr] = a0.x; Ast[lc + 1][lr] = a0.y;
        Ast[lc + 2][lr] = a0.z; Ast[lc + 3][lr] = a0.w;
        Ast[lc + 4][lr] = a1.x; Ast[lc + 5][lr] = a1.y;
        Ast[lc + 6][lr] = a1.z; Ast[lc + 7][lr] = a1.w;
        Bst[lc + 0][lr] = b0.x; Bst[lc + 1][lr] = b0.y;
        Bst[lc + 2][lr] = b0.z; Bst[lc + 3][lr] = b0.w;
        Bst[lc + 4][lr] = b1.x; Bst[lc + 5][lr] = b1.y;
        Bst[lc + 6][lr] = b1.z; Bst[lc + 7][lr] = b1.w;
        __syncthreads();
#pragma unroll
        for (int kk = 0; kk < 32; kk++) {
            float av[4], bv[4];
            *(float4*)av = *(const float4*)&Ast[kk][ty * 4];
            *(float4*)bv = *(const float4*)&Bst[kk][tx * 4];
#pragma unroll
            for (int i = 0; i < 4; i++)
#pragma unroll
                for (int j = 0; j < 4; j++)
                    acc[i][j] = fmaf(av[i], bv[j], acc[i][j]);
        }
        __syncthreads();
    }
#pragma unroll
    for (int i = 0; i < 4; i++) {
        int b = ty * 4 + i;
#pragma unroll
        for (int j = 0; j < 4; j++) {
            int v = v0 + tx * 4 + j;
            if (v < NV) logits[(long)b * LS + v] = acc[i][j] + b_out[v];
        }
    }
}

__global__ __launch_bounds__(256) void k_lse(
    const float* __restrict__ logits, float* __restrict__ lse) {
    const int b = blockIdx.x;
    const float* row = logits + (long)b * LS;
    float m = -1e30f, s = 0.f;
    for (int v = threadIdx.x; v < NV; v += 256) {
        float x = row[v];
        if (x > m) { s = s * __expf(m - x) + 1.f; m = x; }
        else s += __expf(x - m);
    }
    for (int off = 32; off; off >>= 1) {
        float m2 = __shfl_down(m, off);
        float s2 = __shfl_down(s, off);
        float M = fmaxf(m, m2);
        s = s * __expf(m - M) + s2 * __expf(m2 - M);
        m = M;
    }
    __shared__ float ms[4], ss[4];
    int wid = threadIdx.x >> 6, lane = threadIdx.x & 63;
    if (lane == 0) { ms[wid] = m; ss[wid] = s; }
    __syncthreads();
    if (threadIdx.x == 0) {
        m = ms[0]; s = ss[0];
        for (int w = 1; w < 4; w++) {
            float M = fmaxf(m, ms[w]);
            s = s * __expf(m - M) + ss[w] * __expf(ms[w] - M);
            m = M;
        }
        lse[b] = m + __logf(s);
    }
}

__global__ __launch_bounds__(64) void k_loss(
    const float* __restrict__ logits, const float* __restrict__ lse,
    const int* __restrict__ tlines, float* __restrict__ out0) {
    int b = threadIdx.x;
    float v = logits[(long)b * LS + tlines[b]] - lse[b];
    for (int off = 32; off; off >>= 1) v += __shfl_down(v, off);
    if (b == 0) out0[0] = -v * (1.f / 64.f);
}

// S[t][h][e] = sum_b ht[b][h]*hs[t][b][e] via bf16 MFMA on hsx ([t][k][b] bf16).
__global__ __launch_bounds__(256) void k_attn(
    const short* __restrict__ hsts, float* __restrict__ eS0, float* __restrict__ part) {
    const int hti = blockIdx.x >> 3, eti = blockIdx.x & 7;
    const int tc = blockIdx.y;
    const int w = threadIdx.x >> 6, l = threadIdx.x & 63;
    const int l15 = l & 15, lq = l >> 4;
    short8 a[4][2];
#pragma unroll
    for (int mi = 0; mi < 4; mi++)
#pragma unroll
        for (int kb = 0; kb < 2; kb++) {
            int h = hti * 64 + mi * 16 + l15;
            int b = kb * 32 + lq * 8;
            a[mi][kb] = *(const short8*)(hsts + ((long)TE * HD + h) * BS + b);
        }
    const int eg = eti * 64 + w * 16 + l15;
    float ps[4][4] = {};
    for (int dt = 0; dt < 64; dt++) {
        int t = tc * 64 + dt;
        short8 bf0 = *(const short8*)(hsts + ((long)t * HD + eg) * BS + lq * 8);
        short8 bf1 = *(const short8*)(hsts + ((long)t * HD + eg) * BS + 32 + lq * 8);
#pragma unroll
        for (int mi = 0; mi < 4; mi++) {
            floatx4 acc = {0.f, 0.f, 0.f, 0.f};
            acc = mm_bf16(a[mi][0], bf0, acc);
            acc = mm_bf16(a[mi][1], bf1, acc);
#pragma unroll
            for (int r = 0; r < 4; r++) {
                float e = __expf(acc[r]);
                ps[mi][r] += e;
                if (t == 0) {
                    int hg = hti * 64 + mi * 16 + lq * 4 + r;
                    eS0[(long)hg * HD + eg] = e;
                }
            }
        }
    }
#pragma unroll
    for (int mi = 0; mi < 4; mi++)
#pragma unroll
        for (int r = 0; r < 4; r++) {
            int hg = hti * 64 + mi * 16 + lq * 4 + r;
            part[(long)tc * 262144 + (long)hg * HD + eg] = ps[mi][r];
        }
}

__global__ __launch_bounds__(256) void k_attn_fin(
    const float* __restrict__ eS0, const float* __restrict__ part,
    float* __restrict__ outat) {
    long i = (long)blockIdx.x * 256 + threadIdx.x;
    float d = part[i] + part[262144 + i] + part[2L * 262144 + i] + part[3L * 262144 + i];
    outat[i] = eS0[i] / d;
}

extern "C" void kernel_launch(void* const* d_in, const int* in_sizes, int n_in,
                              void* d_out, int out_size, void* d_ws, size_t ws_size,
                              hipStream_t stream) {
    (void)in_sizes; (void)n_in; (void)out_size; (void)ws_size;
    const int* input_lines  = (const int*)d_in[0];
    const int* target_lines = (const int*)d_in[1];
    const float* emb_in  = (const float*)d_in[2];
    const float* emb_tgt = (const float*)d_in[3];
    const float* W_ih = (const float*)d_in[4];
    const float* W_hh = (const float*)d_in[5];
    const float* b_ih = (const float*)d_in[6];
    const float* b_hh = (const float*)d_in[7];
    const float* W_out = (const float*)d_in[8];
    const float* b_out = (const float*)d_in[9];
    float* out = (float*)d_out;
    char* ws = (char*)d_ws;

    short*    Wc     = (short*)   (ws + 0);           //  4,194,304 B
    unsigned* hsx    = (unsigned*)(ws + 4194304);     // 16,842,752 B  [257][512][32] packed bf16x2
    float*    h255   = (float*)   (ws + 21037056);    //    131,072 B
    float*    logits = (float*)   (ws + 21168128);    // 12,877,824 B
    float*    lse    = (float*)   (ws + 34045952);    //        256 B
    float*    eS0    = (float*)   (ws + 34046208);    //  1,048,576 B
    float*    part   = (float*)   (ws + 35094784);    //  4,194,304 B
    unsigned* cnt    = (unsigned*)(ws + 39289088);    //      4,112 B

    hipLaunchKernelGGL(k_zero, dim3(5), dim3(256), 0, stream, cnt, 4 * 257);
    hipLaunchKernelGGL(k_prep, dim3(2048), dim3(256), 0, stream, W_ih, W_hh, Wc);
    hipLaunchKernelGGL(k_enc, dim3(128), dim3(256), 0, stream,
                       input_lines, target_lines, emb_in, emb_tgt, Wc,
                       b_ih, b_hh, hsx, h255, cnt);
    hipLaunchKernelGGL(k_logits, dim3(786), dim3(256), 0, stream,
                       h255, W_out, b_out, logits);
    hipLaunchKernelGGL(k_lse, dim3(64), dim3(256), 0, stream, logits, lse);
    hipLaunchKernelGGL(k_loss, dim3(1), dim3(64), 0, stream,
                       logits, lse, target_lines, out);
    hipLaunchKernelGGL(k_attn, dim3(64, 4), dim3(256), 0, stream,
                       (const short*)hsx, eS0, part);
    hipLaunchKernelGGL(k_attn_fin, dim3(1024), dim3(256), 0, stream, eS0, part, out + 1);
}